// Round 16
// baseline (406.630 us; speedup 1.0000x reference)
//
#include <hip/hip_runtime.h>
#include <hip/hip_bf16.h>

#define NN 50000
#define NE 600000
#define DD 128

#define NBLK 1024            // 4 blocks/CU x 256 CU -> one resident cohort
#define NTHR 256
#define NWAVES (NBLK * 4)
#define POISON 0xAAAAAAAAu
#define FLAG_MAGIC 0x5A5A0001u

typedef __attribute__((ext_vector_type(8))) short bf16x8;
typedef __attribute__((ext_vector_type(4))) float f32x4;

__device__ __forceinline__ short f2bf(float f) {
    union { float f; unsigned u; } v; v.f = f;
    return (short)((v.u + 0x7FFFu + ((v.u >> 16) & 1u)) >> 16);  // RNE f32->bf16
}

// ONE kernel for everything. Lessons encoded:
//  - r10: __launch_bounds__ min-waves clamp spills -> plain (256).
//  - r14: 32 reg-resident W1 fragments (128 VGPR) + 32 AGPR acc -> ~200 regs
//    -> 2 waves/SIMD (20% occ). Fix: W1 fragments live in LDS, pre-swizzled
//    to per-lane order so inner loop does conflict-free ds_read_b128 with
//    immediate offsets; opaque asm on fofs stops LICM from re-hoisting them.
//  - r6/r14: ~100us of multi-launch overhead -> single launch; ws init is
//    claimed by the FIRST block to finish (atomicCAS on the 0xAA poison),
//    so no dispatch-order assumption (guide §6 G16).
__global__ __launch_bounds__(256) void fused_all(
    const float* __restrict__ x, const float* __restrict__ W1,
    const float* __restrict__ b1, const float* __restrict__ W2,
    const float* __restrict__ b2, const int* __restrict__ eidx,
    const float* __restrict__ xm, const float* __restrict__ xs,
    float* __restrict__ ws, float* __restrict__ out)
{
    // frag_lds[f][lane][j]: f = c*8+t (32 frags), 64 lanes, 8 bf16 = 32 KB
    __shared__ __align__(16) short frag_lds[32 * 64 * 8];

    const int tid = threadIdx.x;
    float* wsf = ws;
    unsigned* wsu = (unsigned*)ws;

    // --- stage W1 fragments into LDS in per-lane fragment order ---
    // frag (c,t), lane (ln,kg), elem j holds W1[32c+8kg+j][16t+ln] as bf16.
    for (int i = tid; i < 32 * 64; i += NTHR) {
        const int f = i >> 6, lane_s = i & 63;
        const int c = f >> 3, t = f & 7;
        const int ln_s = lane_s & 15, kg_s = lane_s >> 4;
#pragma unroll
        for (int j = 0; j < 8; ++j)
            frag_lds[i * 8 + j] = f2bf(W1[(32 * c + 8 * kg_s + j) * 128 + 16 * t + ln_s]);
    }
    __syncthreads();

    const int lane = tid & 63;
    const int ln = lane & 15;   // edge-in-tile / C-col
    const int kg = lane >> 4;   // k-group

    float b1v[8], w2v[8];
#pragma unroll
    for (int t = 0; t < 8; ++t) { b1v[t] = b1[16 * t + ln]; w2v[t] = W2[16 * t + ln]; }
    const float b2v = b2[0];

    const int wave = blockIdx.x * 4 + (tid >> 6);
    float lsum = 0.f;
    int fofs = 0;   // always 0, but opaque to the compiler (blocks LICM)

    for (int tile = wave; tile < NE / 16; tile += NWAVES) {
        asm volatile("" : "+v"(fofs));
        const bf16x8* fbase = (const bf16x8*)&frag_lds[fofs + lane * 8];

        const int e = tile * 16 + ln;
        const int si = eidx[e];
        const int di = eidx[NE + e];
        const float* ps = x + (size_t)si * DD;
        const float* pd = x + (size_t)di * DD;

        f32x4 acc[8];
#pragma unroll
        for (int t = 0; t < 8; ++t) acc[t] = (f32x4){0.f, 0.f, 0.f, 0.f};

#pragma unroll
        for (int c = 0; c < 4; ++c) {
            const int ko = 32 * c + 8 * kg;  // same k-formula as staged B frags
            const float4 s0 = *(const float4*)(ps + ko);
            const float4 s1 = *(const float4*)(ps + ko + 4);
            const float4 d0 = *(const float4*)(pd + ko);
            const float4 d1 = *(const float4*)(pd + ko + 4);
            bf16x8 af;
            af[0] = f2bf(fmaxf(s0.x * d0.x, 0.f));
            af[1] = f2bf(fmaxf(s0.y * d0.y, 0.f));
            af[2] = f2bf(fmaxf(s0.z * d0.z, 0.f));
            af[3] = f2bf(fmaxf(s0.w * d0.w, 0.f));
            af[4] = f2bf(fmaxf(s1.x * d1.x, 0.f));
            af[5] = f2bf(fmaxf(s1.y * d1.y, 0.f));
            af[6] = f2bf(fmaxf(s1.z * d1.z, 0.f));
            af[7] = f2bf(fmaxf(s1.w * d1.w, 0.f));
#pragma unroll
            for (int t = 0; t < 8; ++t) {
                const bf16x8 wfrag = fbase[(c * 8 + t) * 64];  // ds_read_b128, imm offset
                acc[t] = __builtin_amdgcn_mfma_f32_16x16x32_bf16(af, wfrag, acc[t], 0, 0, 0);
            }
        }

        // layer 2: z[row] = sum_n relu(acc + b1) * W2 ; C: col=ln, row=kg*4+r
#pragma unroll
        for (int r = 0; r < 4; ++r) {
            float p = 0.f;
#pragma unroll
            for (int t = 0; t < 8; ++t)
                p += fmaxf(acc[t][r] + b1v[t], 0.f) * w2v[t];
            p += __shfl_xor(p, 1);
            p += __shfl_xor(p, 2);
            p += __shfl_xor(p, 4);
            p += __shfl_xor(p, 8);
            const float z = p + b2v;
            const float l = fminf(__logf(1.f + __expf(-z)), 27.631021115928547f);
            lsum += (ln == 0) ? l : 0.f;
        }
    }
    lsum += __shfl_xor(lsum, 16);
    lsum += __shfl_xor(lsum, 32);

    // --- KL tail: coalesced stream, fills edge-imbalance tail ---
    float ksum = 0.f;
    const int total4 = NN * DD / 4;
    for (int i = blockIdx.x * NTHR + tid; i < total4; i += NBLK * NTHR) {
        const float4 m = ((const float4*)xm)[i];
        const float4 v = ((const float4*)xs)[i];
        ksum += 1.f + 2.f * __logf(v.x + 1e-6f) - m.x * m.x - v.x * v.x;
        ksum += 1.f + 2.f * __logf(v.y + 1e-6f) - m.y * m.y - v.y * v.y;
        ksum += 1.f + 2.f * __logf(v.z + 1e-6f) - m.z * m.z - v.z * v.z;
        ksum += 1.f + 2.f * __logf(v.w + 1e-6f) - m.w * m.w - v.w * v.w;
    }
#pragma unroll
    for (int m = 1; m < 64; m <<= 1) ksum += __shfl_xor(ksum, m);

    // --- init claim: FIRST arriving block zeroes accumulators (CAS on the
    // 0xAA poison), everyone else waits for the magic flag. No dependence on
    // dispatch order; every block reaches this point in finite time. ---
    if (tid == 0) {
        const unsigned old = atomicCAS(&wsu[2], POISON, FLAG_MAGIC - 1u);
        if (old == POISON) {
            wsf[0] = 0.f;        // edge-loss sum
            wsf[1] = 0.f;        // kl sum
            wsu[3] = 0u;         // completion counter
            __threadfence();
            atomicExch(&wsu[2], FLAG_MAGIC);
        } else {
            while (atomicAdd(&wsu[2], 0u) != FLAG_MAGIC) {}
        }
    }
    __syncthreads();

    if (lane == 0) {
        atomicAdd(&wsf[0], lsum);
        atomicAdd(&wsf[1], ksum);
    }
    __threadfence();
    __syncthreads();

    // --- last block combines and writes the scalar output ---
    if (tid == 0) {
        const unsigned done = atomicAdd(&wsu[3], 1u);
        if (done == (unsigned)(gridDim.x - 1)) {
            __threadfence();
            const float es = atomicAdd(&wsf[0], 0.f);
            const float ks = atomicAdd(&wsf[1], 0.f);
            out[0] = es * (1.f / NE) - 0.5f * ks * (1.f / NN);
        }
    }
}

extern "C" void kernel_launch(void* const* d_in, const int* in_sizes, int n_in,
                              void* d_out, int out_size, void* d_ws, size_t ws_size,
                              hipStream_t stream) {
    const float* x  = (const float*)d_in[0];
    const float* xm = (const float*)d_in[1];
    const float* xs = (const float*)d_in[2];
    const float* W1 = (const float*)d_in[3];
    const float* b1 = (const float*)d_in[4];
    const float* W2 = (const float*)d_in[5];
    const float* b2 = (const float*)d_in[6];
    const int* eidx = (const int*)d_in[7];
    // d_in[8] (edge_index_batch) is all zeros with B=1 -> pooling collapses; unused.
    float* out = (float*)d_out;
    float* ws = (float*)d_ws;

    hipLaunchKernelGGL(fused_all, dim3(NBLK), dim3(NTHR), 0, stream,
                       x, W1, b1, W2, b2, eidx, xm, xs, ws, out);
}